// Round 13
// baseline (236.689 us; speedup 1.0000x reference)
//
#include <hip/hip_runtime.h>
#include <stdint.h>

// NCA: B=8, C=16, H=W=128, hidden=128, 8 steps.
// ws: [0,8MB) midA | [8,16MB) midB | +512KB mid3cA | +512KB mid3cB |
//     +128KB preA | +128KB preB | +2MB mask | +40KB f16 weights. ~19.3 MB.
// Base = round-11 (220.9us, bit-exact): r6 math + r10 mask tails + XCD
// swizzle. Round 13 delta: block-level cooperative LDS staging of the
// 3-row x 16-ch tap window (6 float4 loads/thread + 1 barrier) replaces
// ~72 per-lane scalar global tap loads -> one latency segment WITHOUT
// the r12 register cost. Staged values are the same floats -> bit-exact.

#define BATCH 8
#define CH 16
#define HT 128
#define WD 128
#define HIDN 128
#define PLANE (HT*WD)
#define IMG (CH*PLANE)
#define NELEM (BATCH*IMG)
#define NPIX (BATCH*PLANE)
#define WORDS_PER_STEP (NELEM/32)
#define NSTEPS 8
#define STEP_BLOCKS (NPIX/128)          // 1024 = 8 XCDs x 128 rows
#define MASK_BLOCKS (WORDS_PER_STEP/256) // 256

// ---- step kernel LDS ----
// Per-wave (intra-wave only): P hi/lo 2304B each + kcm/kfl 432B each = 5504B.
// Per-block stage: [3 rows][16 ch][140 words] fp32 = 26880B
//   (4-word front guard for col -1, tail guard for col 128; stride 140:
//    140%32=12 -> consume reads land 2 lanes/bank = free).
#define PSTR 72
#define PLO_OFF 2304
#define KCM_OFF 4608
#define KF_OFF  5056
#define WREG    5504
#define SGSTR   140                     // words per (row,ch) line
#define SGROW   (16*SGSTR)              // 2240 words per row
#define SGOFF   (4*WREG)                // stage byte offset in smem
#define SMEM_SZ (4*WREG + 3*SGROW*4)    // 48896 B -> 3 blocks/CU

#define MEM_FENCE() asm volatile("" ::: "memory")

typedef _Float16 f16x8 __attribute__((ext_vector_type(8)));
typedef _Float16 f16x4 __attribute__((ext_vector_type(4)));
typedef float    f32x4 __attribute__((ext_vector_type(4)));

struct Keys { unsigned k[2*NSTEPS]; };

__host__ __device__ __forceinline__ unsigned rotl32u(unsigned v, int r) {
  return (v << r) | (v >> (32 - r));
}

// JAX threefry2x32 (20 rounds).
__host__ __device__ __forceinline__ void tf2x32(unsigned k0, unsigned k1,
                                                unsigned c0, unsigned c1,
                                                unsigned &o0, unsigned &o1) {
  const unsigned ks2 = k0 ^ k1 ^ 0x1BD11BDAu;
  unsigned x0 = c0 + k0, x1 = c1 + k1;
  x0 += x1; x1 = rotl32u(x1, 13); x1 ^= x0;
  x0 += x1; x1 = rotl32u(x1, 15); x1 ^= x0;
  x0 += x1; x1 = rotl32u(x1, 26); x1 ^= x0;
  x0 += x1; x1 = rotl32u(x1,  6); x1 ^= x0;
  x0 += k1; x1 += ks2 + 1u;
  x0 += x1; x1 = rotl32u(x1, 17); x1 ^= x0;
  x0 += x1; x1 = rotl32u(x1, 29); x1 ^= x0;
  x0 += x1; x1 = rotl32u(x1, 16); x1 ^= x0;
  x0 += x1; x1 = rotl32u(x1, 24); x1 ^= x0;
  x0 += ks2; x1 += k0 + 2u;
  x0 += x1; x1 = rotl32u(x1, 13); x1 ^= x0;
  x0 += x1; x1 = rotl32u(x1, 15); x1 ^= x0;
  x0 += x1; x1 = rotl32u(x1, 26); x1 ^= x0;
  x0 += x1; x1 = rotl32u(x1,  6); x1 ^= x0;
  x0 += k0; x1 += k1 + 3u;
  x0 += x1; x1 = rotl32u(x1, 17); x1 ^= x0;
  x0 += x1; x1 = rotl32u(x1, 29); x1 ^= x0;
  x0 += x1; x1 = rotl32u(x1, 16); x1 ^= x0;
  x0 += x1; x1 = rotl32u(x1, 24); x1 ^= x0;
  x0 += k1; x1 += ks2 + 4u;
  x0 += x1; x1 = rotl32u(x1, 13); x1 ^= x0;
  x0 += x1; x1 = rotl32u(x1, 15); x1 ^= x0;
  x0 += x1; x1 = rotl32u(x1, 26); x1 ^= x0;
  x0 += x1; x1 = rotl32u(x1,  6); x1 ^= x0;
  x0 += ks2; x1 += k0 + 5u;
  o0 = x0; o1 = x1;
}

// One mask word, bit-identical to the baseline mask_kernel's formula.
__device__ __forceinline__ unsigned mask_word(unsigned k0, unsigned k1,
                                              unsigned wid) {
  const unsigned base = wid << 5;
  unsigned word = 0u;
  #pragma unroll 4
  for (int i = 0; i < 32; ++i) {
    unsigned b1x, b2x;
    tf2x32(k0, k1, 0u, base + (unsigned)i, b1x, b2x);
    unsigned bits = b1x ^ b2x;
    word |= (((bits >> 9) != 0u) ? 1u : 0u) << i;
  }
  return word;
}

// wpack + step-0 mask in one launch. Blocks [0,40): weight packing;
// blocks [40,40+256): step-0 mask words.
__global__ __launch_bounds__(256) void wpack_kernel(
    const float* __restrict__ w1, const float* __restrict__ w2,
    _Float16* __restrict__ w1fh, _Float16* __restrict__ w1fl,
    _Float16* __restrict__ w2fh, _Float16* __restrict__ w2fl,
    unsigned* __restrict__ mask0, unsigned mk0, unsigned mk1) {
  if (blockIdx.x >= 40) {
    const unsigned wid = (blockIdx.x - 40) * 256u + threadIdx.x; // < 65536
    mask0[wid] = mask_word(mk0, mk1, wid);
    return;
  }
  int t = blockIdx.x * 256 + threadIdx.x;   // 10240 threads
  if (t < 8192) {
    int lane = (t >> 3) & 63, i = t & 7;
    int kt = t >> 12, nt = (t >> 9) & 7;
    int k = kt * 32 + (lane >> 4) * 8 + i;
    int n = nt * 16 + (lane & 15);
    float v = (k < 48) ? w1[n * 48 + k] : 0.f;
    _Float16 h = (_Float16)v;
    w1fh[t] = h;
    w1fl[t] = (_Float16)(v - (float)h);
  } else {
    int u = t - 8192;                        // 2048 threads
    int lane = (u >> 3) & 63, i = u & 7;
    int kt = u >> 9;
    int g = (lane >> 4) & 3;
    int o = lane & 15;
    int kk = (i < 4) ? (4 * g + i) : (16 + 4 * g + (i - 4));
    float v = w2[o * HIDN + kt * 32 + kk];
    _Float16 h = (_Float16)v;
    w2fh[u] = h;
    w2fl[u] = (_Float16)(v - (float)h);
  }
}

// MFMA step kernel — r11 math + cooperative LDS tap staging.
// Blocks [0,1024): step work, b = blk&7 (XCD-resident image), y = blk>>3.
// Blocks [1024,1024+256) (when s<7): generate NEXT step's mask words.
__global__ __launch_bounds__(256, 3) void step_mfma(
    const float* __restrict__ s,
    const f16x8* __restrict__ w1fh, const f16x8* __restrict__ w1fl,
    const f16x8* __restrict__ w2fh, const f16x8* __restrict__ w2fl,
    const float* __restrict__ bias1, const float* __restrict__ bias2,
    const unsigned* __restrict__ mask,   // this step's words (read)
    unsigned* __restrict__ maskN,        // next step's words (tail writes)
    const unsigned kn0, const unsigned kn1,  // next step's threefry key
    float* __restrict__ mid,
    const float* __restrict__ mid3cR,   // prev step's ch3 snapshot
    float* __restrict__ mid3cW,         // this step's ch3 snapshot
    const unsigned char* __restrict__ preR,  // prev step's pre bits
    unsigned char* __restrict__ preW,        // this step's pre bits
    const int hasKill) {
  if (blockIdx.x >= STEP_BLOCKS) {     // mask-gen tail block
    const unsigned wid = (blockIdx.x - STEP_BLOCKS) * 256u + threadIdx.x;
    maskN[wid] = mask_word(kn0, kn1, wid);
    return;
  }

  __shared__ __align__(16) char smem[SMEM_SZ];
  const int tid = threadIdx.x;
  const int wv = tid >> 6;
  const int l  = tid & 63;
  const int p  = l & 15;        // MFMA row/col lane index
  const int g  = l >> 4;        // lane group (k-group for frags)
  char* wb = smem + wv * WREG;
  _Float16* Phi = (_Float16*)wb;
  _Float16* Plo = (_Float16*)(wb + PLO_OFF);
  float*    kcm = (float*)(wb + KCM_OFF);   // [3][36] col-max of 3 rows
  float*    kfl = (float*)(wb + KF_OFF);    // [3][36] kill factors
  float*    stg = (float*)(smem + SGOFF);   // [3][16][140] tap stage

  // XCD-residency mapping: image b lives on XCD (blockIdx%8) every step.
  const int b  = (int)(blockIdx.x & 7);
  const int y  = (int)(blockIdx.x >> 3);
  const int x0 = wv * 32;
  const int pid0 = ((b << 7) + y) * 128 + x0;   // wave's first pixel
  const bool yu = (y > 0), yd = (y < HT - 1);

  // ---- cooperative tap staging: rows y-1..y+1 x 16ch x 128 cols ----
  // 1536 float4 units over 256 threads = 6 each; one latency segment,
  // ~24 transient VGPRs (unlike r12's 72 persistent tap registers).
  {
    const float* sb = s + b * IMG;
    #pragma unroll
    for (int uu = 0; uu < 6; ++uu) {
      const int u = tid + uu * 256;            // < 1536
      const int r = u >> 9;                    // 0..2
      const int ch = (u >> 5) & 15;
      const int c4 = (u & 31) * 4;
      const int ry = y - 1 + r;
      if ((unsigned)ry < HT) {                 // OOB rows left garbage;
        const float4 v = *(const float4*)(sb + ch * PLANE + ry * WD + c4);
        *(float4*)(stg + r * SGROW + ch * SGSTR + 4 + c4) = v;
      }                                        // consume predicates them out
    }
  }

  // ---- kill table via colmax (global loads, same as r11) ----
  if (hasKill) {
    const float* m3 = mid3cR + b * PLANE;
    #pragma unroll
    for (int rr = 0; rr < 2; ++rr) {
      const int e = l + rr * 64;
      if (e < 108) {
        const int kr = e / 36;            // output row y-1+kr
        const int kc = e - kr * 36;       // col x0-2+kc
        const int xx = x0 - 2 + kc;
        float cm = -1e30f;
        if ((unsigned)xx < WD) {
          #pragma unroll
          for (int dr = -1; dr <= 1; ++dr) {
            const int ry = y - 1 + kr + dr;
            if ((unsigned)ry < HT) cm = fmaxf(cm, m3[ry * WD + xx]);
          }
        }
        kcm[kr * 36 + kc] = cm;
      }
    }
    MEM_FENCE();  // kcm writes before kcm reads (intra-wave)
    const unsigned char* prb = preR + b * PLANE;
    #pragma unroll
    for (int rr = 0; rr < 2; ++rr) {
      const int e = l + rr * 64;
      if (e < 102) {
        const int kr = e / 34;
        const int kc = e - kr * 34;
        const int yy = y - 1 + kr;
        const int xx = x0 - 1 + kc;
        float kf = 0.f;
        if ((unsigned)yy < HT && (unsigned)xx < WD) {
          const float* c0 = kcm + kr * 36 + kc;
          float mx = fmaxf(fmaxf(c0[0], c0[1]), c0[2]);
          kf = ((mx > 0.1f) && prb[yy * WD + xx]) ? 1.f : 0.f;
        }
        kfl[kr * 36 + kc] = kf;
      }
    }
  } else {
    #pragma unroll
    for (int rr = 0; rr < 2; ++rr) {
      const int e = l + rr * 64;
      if (e < 108) kfl[e] = 1.f;          // [3][36] all-alive
    }
  }

  // Early independent loads.
  const float4 b2q = *(const float4*)(bias2 + g * 4);
  unsigned mw[4];
  #pragma unroll
  for (int cc = 0; cc < 4; ++cc)
    mw[cc] = mask[((b * CH + g * 4 + cc) * HT + y) * (WD / 32) + (x0 >> 5)];

  // Zero-pad P feats 48..63 (16 rows x {hi,lo}): one 16B chunk per lane.
  {
    uint4 z; z.x = 0u; z.y = 0u; z.z = 0u; z.w = 0u;
    _Float16* zb = (l & 32) ? Plo : Phi;
    *(uint4*)(zb + (l & 15) * PSTR + 48 + ((l >> 4) & 1) * 8) = z;
  }

  __syncthreads();   // stage (cross-wave) + kfl/pad complete

  // ---- perceive both tiles from the LDS stage, tile-sequenced P ----
  float sctr[2][4];
  float premax[2] = {-1e30f, -1e30f};
  f16x8 pbh[2][2], pbl[2][2];   // P B-fragments (hi/lo, kt=0/1) per tile
  #pragma unroll
  for (int t = 0; t < 2; ++t) {
    const int xt = x0 + 16 * t + p;
    const bool xl = (xt > 0), xr = (xt < WD - 1);
    float kf9[9];
    {
      const int kc = 16 * t + p;
      #pragma unroll
      for (int dy2 = 0; dy2 < 3; ++dy2)
        #pragma unroll
        for (int dx2 = 0; dx2 < 3; ++dx2)
          kf9[dy2 * 3 + dx2] = kfl[dy2 * 36 + kc + dx2];
    }
    f16x4 vh0, vh1, vh2, vl0, vl1, vl2;
    #pragma unroll
    for (int cc = 0; cc < 4; ++cc) {
      const int c = g * 4 + cc;
      const float* sg = stg + c * SGSTR + 4 + xt;   // row 0 (y-1), center col
      float a11 = sg[SGROW] * kf9[4];
      float a00 = ((yu && xl) ? sg[-1]            : 0.f) * kf9[0];
      float a01 = (yu         ? sg[0]             : 0.f) * kf9[1];
      float a02 = ((yu && xr) ? sg[1]             : 0.f) * kf9[2];
      float a10 = (xl         ? sg[SGROW - 1]     : 0.f) * kf9[3];
      float a12 = (xr         ? sg[SGROW + 1]     : 0.f) * kf9[5];
      float a20 = ((yd && xl) ? sg[2 * SGROW - 1] : 0.f) * kf9[6];
      float a21 = (yd         ? sg[2 * SGROW]     : 0.f) * kf9[7];
      float a22 = ((yd && xr) ? sg[2 * SGROW + 1] : 0.f) * kf9[8];
      float sx = (a02 - a00) + 2.f * (a12 - a10) + (a22 - a20);
      float sy = (a20 - a00) + 2.f * (a21 - a01) + (a22 - a02);
      sctr[t][cc] = a11;
      _Float16 h0 = (_Float16)a11;
      _Float16 h1 = (_Float16)sx;
      _Float16 h2 = (_Float16)sy;
      vh0[cc] = h0; vl0[cc] = (_Float16)(a11 - (float)h0);
      vh1[cc] = h1; vl1[cc] = (_Float16)(sx - (float)h1);
      vh2[cc] = h2; vl2[cc] = (_Float16)(sy - (float)h2);
      if (g == 0 && cc == 3) {   // alive channel: pre-update maxpool (killed)
        float m0 = fmaxf(fmaxf(a00, a01), fmaxf(a02, a10));
        float m1 = fmaxf(fmaxf(a11, a12), fmaxf(a20, a21));
        premax[t] = fmaxf(fmaxf(m0, m1), a22);
      }
    }
    *(f16x4*)(Phi + p * PSTR + 4 * g)      = vh0;
    *(f16x4*)(Phi + p * PSTR + 16 + 4 * g) = vh1;
    *(f16x4*)(Phi + p * PSTR + 32 + 4 * g) = vh2;
    *(f16x4*)(Plo + p * PSTR + 4 * g)      = vl0;
    *(f16x4*)(Plo + p * PSTR + 16 + 4 * g) = vl1;
    *(f16x4*)(Plo + p * PSTR + 32 + 4 * g) = vl2;
    MEM_FENCE();  // P writes before B-frag reads (intra-wave)
    const _Float16* prow = Phi + p * PSTR;
    const _Float16* lrow = Plo + p * PSTR;
    pbh[t][0] = *(const f16x8*)(prow + g * 8);
    pbh[t][1] = *(const f16x8*)(prow + 32 + g * 8);
    pbl[t][0] = *(const f16x8*)(lrow + g * 8);
    pbl[t][1] = *(const f16x8*)(lrow + 32 + g * 8);
    MEM_FENCE();  // B-frag reads before tile1 P writes
  }

  // ---- GEMM1 (swapped): acc[t][nt] = bias1 + W1 x P, split-f16.
  f32x4 acc[2][8];
  #pragma unroll
  for (int nt = 0; nt < 8; ++nt) {
    const float4 bq = *(const float4*)(bias1 + nt * 16 + 4 * g);
    f32x4 v = {bq.x, bq.y, bq.z, bq.w};
    acc[0][nt] = v;
    acc[1][nt] = v;
  }
  #pragma unroll
  for (int nt = 0; nt < 8; ++nt) {
    f16x8 w1h0 = w1fh[nt * 64 + l];
    f16x8 w1h1 = w1fh[512 + nt * 64 + l];
    f16x8 w1l0 = w1fl[nt * 64 + l];
    f16x8 w1l1 = w1fl[512 + nt * 64 + l];
    #pragma unroll
    for (int t = 0; t < 2; ++t) {
      acc[t][nt] = __builtin_amdgcn_mfma_f32_16x16x32_f16(w1h0, pbh[t][0], acc[t][nt], 0, 0, 0);
      acc[t][nt] = __builtin_amdgcn_mfma_f32_16x16x32_f16(w1h1, pbh[t][1], acc[t][nt], 0, 0, 0);
      acc[t][nt] = __builtin_amdgcn_mfma_f32_16x16x32_f16(w1l0, pbh[t][0], acc[t][nt], 0, 0, 0);
      acc[t][nt] = __builtin_amdgcn_mfma_f32_16x16x32_f16(w1l1, pbh[t][1], acc[t][nt], 0, 0, 0);
      acc[t][nt] = __builtin_amdgcn_mfma_f32_16x16x32_f16(w1h0, pbl[t][0], acc[t][nt], 0, 0, 0);
      acc[t][nt] = __builtin_amdgcn_mfma_f32_16x16x32_f16(w1h1, pbl[t][1], acc[t][nt], 0, 0, 0);
    }
  }

  // GEMM2 W2 A-fragments (sigma-packed; shared by both tiles).
  f16x8 w2h[4], w2l[4];
  #pragma unroll
  for (int kt = 0; kt < 4; ++kt) {
    w2h[kt] = w2fh[kt * 64 + l];
    w2l[kt] = w2fl[kt * 64 + l];
  }

  // ---- H in registers + GEMM2 per tile ----
  f32x4 dxr[2];
  #pragma unroll
  for (int t = 0; t < 2; ++t) {
    f16x8 hB[4], lB[4];
    #pragma unroll
    for (int kt = 0; kt < 4; ++kt) {
      #pragma unroll
      for (int i2 = 0; i2 < 4; ++i2) {
        float h0 = fmaxf(acc[t][2 * kt][i2], 0.f);
        _Float16 hh0 = (_Float16)h0;
        hB[kt][i2] = hh0;
        lB[kt][i2] = (_Float16)(h0 - (float)hh0);
        float h1 = fmaxf(acc[t][2 * kt + 1][i2], 0.f);
        _Float16 hh1 = (_Float16)h1;
        hB[kt][4 + i2] = hh1;
        lB[kt][4 + i2] = (_Float16)(h1 - (float)hh1);
      }
    }
    f32x4 accP = {b2q.x, b2q.y, b2q.z, b2q.w};
    f32x4 accQ = {0.f, 0.f, 0.f, 0.f};
    f32x4 accR = {0.f, 0.f, 0.f, 0.f};
    #pragma unroll
    for (int kt = 0; kt < 4; ++kt) {
      accP = __builtin_amdgcn_mfma_f32_16x16x32_f16(w2h[kt], hB[kt], accP, 0, 0, 0);
      accQ = __builtin_amdgcn_mfma_f32_16x16x32_f16(w2l[kt], hB[kt], accQ, 0, 0, 0);
      accR = __builtin_amdgcn_mfma_f32_16x16x32_f16(w2h[kt], lB[kt], accR, 0, 0, 0);
    }
    dxr[t] = (accP + accQ) + accR;
  }

  if (g == 0) {
    preW[pid0 + p]      = (premax[0] > 0.1f) ? 1 : 0;
    preW[pid0 + 16 + p] = (premax[1] > 0.1f) ? 1 : 0;
  }

  // ---- epilogue: lane -> (pixel 16t+p, channels 4g..4g+3). mid stays
  // UNMASKED (next step / step_b applies the kill). Coalesced stores.
  #pragma unroll
  for (int t = 0; t < 2; ++t) {
    const int xt = x0 + 16 * t + p;
    const int rt = y * WD + xt;
    #pragma unroll
    for (int cc = 0; cc < 4; ++cc) {
      const int c = g * 4 + cc;
      float d = dxr[t][cc];
      d = fminf(fmaxf(d, -5.f), 5.f);
      float v = sctr[t][cc] + (((mw[cc] >> (16 * t + p)) & 1u) ? d : 0.f);
      mid[b * IMG + c * PLANE + rt] = v;
      if (g == 0 && cc == 3) mid3cW[pid0 + 16 * t + p] = v;  // ch3 snapshot
    }
  }
}

// Final post-alive maxpool + apply pre&post (reads RAW mid). Block index
// permuted so batch b's blocks land on XCD b (hardware blockIdx%8).
__global__ __launch_bounds__(256) void step_b(
    const float* __restrict__ mid,
    const unsigned char* __restrict__ pre,
    float* __restrict__ out) {
  const unsigned h = blockIdx.x;            // 512 blocks
  const unsigned j = h >> 3;
  const unsigned kl = ((j >> 4) << 7) | ((h & 7) << 4) | (j & 15);
  int t = (int)kl * 256 + threadIdx.x;      // same (cq,b,r) coverage
  int cq = t >> 15;
  int qid = t & 32767;
  int b = qid >> 12;
  int r = qid & 4095;
  int y = r >> 5;
  int x0 = (r & 31) * 4;
  const float* m3 = mid + b * IMG + 3 * PLANE;

  float col[6];
  #pragma unroll
  for (int j2 = 0; j2 < 6; ++j2) {
    int xx = x0 - 1 + j2;
    float m = -1e30f;
    if ((unsigned)xx < WD) {
      #pragma unroll
      for (int dy = -1; dy <= 1; ++dy) {
        int yy = y + dy;
        if ((unsigned)yy < HT) m = fmaxf(m, m3[yy * WD + xx]);
      }
    }
    col[j2] = m;
  }

  const unsigned char* pr = pre + b * PLANE + y * WD + x0;
  float f[4];
  #pragma unroll
  for (int i = 0; i < 4; ++i) {
    float mx = fmaxf(fmaxf(col[i], col[i + 1]), col[i + 2]);
    f[i] = ((mx > 0.1f) && pr[i]) ? 1.f : 0.f;
  }

  #pragma unroll
  for (int cc = 0; cc < 4; ++cc) {
    int c = cq * 4 + cc;
    const float4 v = *(const float4*)&mid[b * IMG + c * PLANE + y * WD + x0];
    float4 w;
    w.x = v.x * f[0]; w.y = v.y * f[1]; w.z = v.z * f[2]; w.w = v.w * f[3];
    *(float4*)&out[b * IMG + c * PLANE + y * WD + x0] = w;
  }
}

extern "C" void kernel_launch(void* const* d_in, const int* in_sizes, int n_in,
                              void* d_out, int out_size, void* d_ws, size_t ws_size,
                              hipStream_t stream) {
  const float* x  = (const float*)d_in[0];
  const float* w1 = (const float*)d_in[1];
  const float* b1 = (const float*)d_in[2];
  const float* w2 = (const float*)d_in[3];
  const float* b2 = (const float*)d_in[4];
  float* out = (float*)d_out;

  char* ws = (char*)d_ws;
  float* midbuf[2];
  midbuf[0] = (float*)ws;
  midbuf[1] = (float*)(ws + (size_t)NELEM * 4);
  float* m3b[2];
  m3b[0] = (float*)(ws + 2 * (size_t)NELEM * 4);
  m3b[1] = m3b[0] + NPIX;
  unsigned char* preb[2];
  preb[0] = (unsigned char*)(ws + 2 * (size_t)NELEM * 4 + 2 * (size_t)NPIX * 4);
  preb[1] = preb[0] + NPIX;
  unsigned* mask = (unsigned*)(ws + 2 * (size_t)NELEM * 4
                                  + 2 * (size_t)NPIX * 4 + 2 * (size_t)NPIX);
  _Float16* w1fh = (_Float16*)((char*)mask
                               + (size_t)NSTEPS * WORDS_PER_STEP * 4);
  _Float16* w1fl = w1fh + 8192;
  _Float16* w2fh = w1fl + 8192;
  _Float16* w2fl = w2fh + 2048;

  // keys = jax.random.split(key(42), 8): keys[j] = threefry2x32((0,42),(0,j))
  Keys keys;
  for (int j = 0; j < NSTEPS; ++j) {
    unsigned a, b;
    tf2x32(0u, 42u, 0u, (unsigned)j, a, b);
    keys.k[2 * j] = a; keys.k[2 * j + 1] = b;
  }

  // wpack + step-0 mask in one launch (40 weight blocks + 256 mask blocks).
  wpack_kernel<<<40 + MASK_BLOCKS, 256, 0, stream>>>(
      w1, w2, w1fh, w1fl, w2fh, w2fl, mask, keys.k[0], keys.k[1]);

  for (int s = 0; s < NSTEPS; ++s) {
    const float* src = (s == 0) ? x : midbuf[(s - 1) & 1];
    const int cur = s & 1, prv = cur ^ 1;
    const bool genNext = (s + 1 < NSTEPS);
    step_mfma<<<STEP_BLOCKS + (genNext ? MASK_BLOCKS : 0), 256, 0, stream>>>(
        src,
        (const f16x8*)w1fh, (const f16x8*)w1fl,
        (const f16x8*)w2fh, (const f16x8*)w2fl,
        b1, b2,
        mask + s * WORDS_PER_STEP,
        mask + (genNext ? (s + 1) : s) * WORDS_PER_STEP,  // tail writes (unused when s=7)
        keys.k[2 * (genNext ? (s + 1) : s)],
        keys.k[2 * (genNext ? (s + 1) : s) + 1],
        midbuf[cur],
        m3b[prv], m3b[cur],     // read prev snapshot, write own
        preb[prv], preb[cur],   // read prev pre bits, write own
        (s > 0) ? 1 : 0);
  }
  step_b<<<NPIX / 256, 256, 0, stream>>>(
      midbuf[(NSTEPS - 1) & 1], preb[(NSTEPS - 1) & 1], out);
}

// Round 14
// 219.852 us; speedup vs baseline: 1.0766x; 1.0766x over previous
//
#include <hip/hip_runtime.h>
#include <stdint.h>

// NCA: B=8, C=16, H=W=128, hidden=128, 8 steps.
// ws: [0,8MB) midA | [8,16MB) midB | +512KB mid3cA | +512KB mid3cB |
//     +128KB preA | +128KB preB | +2MB mask | +40KB f16 weights. ~19.3 MB.
// Base = round-11 (220.9us, bit-exact): r6 math + r10 co-scheduled mask
// tails + XCD-residency swizzle. Round 14 delta: the wpack launch gains
// 1024 prefetch tail blocks that pull the cold input x into the SAME
// XCD L2s the step kernel will read from (b = blk&7 mapping) — fixes the
// observed 42us cold step-0 (r13 profile). Step kernel byte-identical.

#define BATCH 8
#define CH 16
#define HT 128
#define WD 128
#define HIDN 128
#define PLANE (HT*WD)
#define IMG (CH*PLANE)
#define NELEM (BATCH*IMG)
#define NPIX (BATCH*PLANE)
#define WORDS_PER_STEP (NELEM/32)
#define NSTEPS 8
#define STEP_BLOCKS (NPIX/128)          // 1024 = 8 XCDs x 128 rows
#define MASK_BLOCKS (WORDS_PER_STEP/256) // 256
#define PREF_BLOCKS 1024                 // x-prefetch tails on wpack launch

// ---- step kernel LDS (per wave; intra-wave only -> zero barriers) ----
//   P (perceived f16 hi/lo): 16 rows x 72 halves x 2B = 2304 B each
//   kcm / kfl: 3 x 36 fp32 = 432 B each
#define PSTR 72      // 144B rows: 16B-aligned b128 frag reads, spread banks
#define PLO_OFF 2304
#define KCM_OFF 4608
#define KF_OFF  5056
#define WREG    5504 // x4 waves = 22016 B/block

#define MEM_FENCE() asm volatile("" ::: "memory")

typedef _Float16 f16x8 __attribute__((ext_vector_type(8)));
typedef _Float16 f16x4 __attribute__((ext_vector_type(4)));
typedef float    f32x4 __attribute__((ext_vector_type(4)));

struct Keys { unsigned k[2*NSTEPS]; };

__host__ __device__ __forceinline__ unsigned rotl32u(unsigned v, int r) {
  return (v << r) | (v >> (32 - r));
}

// JAX threefry2x32 (20 rounds).
__host__ __device__ __forceinline__ void tf2x32(unsigned k0, unsigned k1,
                                                unsigned c0, unsigned c1,
                                                unsigned &o0, unsigned &o1) {
  const unsigned ks2 = k0 ^ k1 ^ 0x1BD11BDAu;
  unsigned x0 = c0 + k0, x1 = c1 + k1;
  x0 += x1; x1 = rotl32u(x1, 13); x1 ^= x0;
  x0 += x1; x1 = rotl32u(x1, 15); x1 ^= x0;
  x0 += x1; x1 = rotl32u(x1, 26); x1 ^= x0;
  x0 += x1; x1 = rotl32u(x1,  6); x1 ^= x0;
  x0 += k1; x1 += ks2 + 1u;
  x0 += x1; x1 = rotl32u(x1, 17); x1 ^= x0;
  x0 += x1; x1 = rotl32u(x1, 29); x1 ^= x0;
  x0 += x1; x1 = rotl32u(x1, 16); x1 ^= x0;
  x0 += x1; x1 = rotl32u(x1, 24); x1 ^= x0;
  x0 += ks2; x1 += k0 + 2u;
  x0 += x1; x1 = rotl32u(x1, 13); x1 ^= x0;
  x0 += x1; x1 = rotl32u(x1, 15); x1 ^= x0;
  x0 += x1; x1 = rotl32u(x1, 26); x1 ^= x0;
  x0 += x1; x1 = rotl32u(x1,  6); x1 ^= x0;
  x0 += k0; x1 += k1 + 3u;
  x0 += x1; x1 = rotl32u(x1, 17); x1 ^= x0;
  x0 += x1; x1 = rotl32u(x1, 29); x1 ^= x0;
  x0 += x1; x1 = rotl32u(x1, 16); x1 ^= x0;
  x0 += x1; x1 = rotl32u(x1, 24); x1 ^= x0;
  x0 += k1; x1 += ks2 + 4u;
  x0 += x1; x1 = rotl32u(x1, 13); x1 ^= x0;
  x0 += x1; x1 = rotl32u(x1, 15); x1 ^= x0;
  x0 += x1; x1 = rotl32u(x1, 26); x1 ^= x0;
  x0 += x1; x1 = rotl32u(x1,  6); x1 ^= x0;
  x0 += ks2; x1 += k0 + 5u;
  o0 = x0; o1 = x1;
}

// One mask word, bit-identical to the baseline mask_kernel's formula.
__device__ __forceinline__ unsigned mask_word(unsigned k0, unsigned k1,
                                              unsigned wid) {
  const unsigned base = wid << 5;
  unsigned word = 0u;
  #pragma unroll 4
  for (int i = 0; i < 32; ++i) {
    unsigned b1x, b2x;
    tf2x32(k0, k1, 0u, base + (unsigned)i, b1x, b2x);
    unsigned bits = b1x ^ b2x;
    word |= (((bits >> 9) != 0u) ? 1u : 0u) << i;
  }
  return word;
}

// wpack + step-0 mask + x-prefetch in one launch.
// Blocks [0,40): weight packing; [40,296): step-0 mask words;
// [296,1320): prefetch x into XCD-resident L2 (same b=blk&7 mapping as
// step_mfma, so the fill lands in the L2 the consumer will read).
__global__ __launch_bounds__(256) void wpack_kernel(
    const float* __restrict__ xin,
    const float* __restrict__ w1, const float* __restrict__ w2,
    _Float16* __restrict__ w1fh, _Float16* __restrict__ w1fl,
    _Float16* __restrict__ w2fh, _Float16* __restrict__ w2fl,
    unsigned* __restrict__ mask0, unsigned mk0, unsigned mk1) {
  if (blockIdx.x >= 40u + MASK_BLOCKS) {
    const unsigned pb = blockIdx.x - (40u + MASK_BLOCKS);   // < 1024
    const int b = (int)(pb & 7);
    const int y = (int)(pb >> 3);
    float acc = 0.f;
    #pragma unroll
    for (int k = 0; k < 2; ++k) {
      const int u = (int)threadIdx.x + k * 256;   // < 512
      const int ch = u >> 5;
      const int c4 = (u & 31) * 4;
      const float4 v = *(const float4*)(xin + (size_t)b * IMG
                                        + ch * PLANE + y * WD + c4);
      acc += (v.x + v.y) + (v.z + v.w);
    }
    asm volatile("" :: "v"(acc));   // keep prefetch loads alive (no DCE)
    return;
  }
  if (blockIdx.x >= 40) {
    const unsigned wid = (blockIdx.x - 40) * 256u + threadIdx.x; // < 65536
    mask0[wid] = mask_word(mk0, mk1, wid);
    return;
  }
  int t = blockIdx.x * 256 + threadIdx.x;   // 10240 threads
  if (t < 8192) {
    int lane = (t >> 3) & 63, i = t & 7;
    int kt = t >> 12, nt = (t >> 9) & 7;
    int k = kt * 32 + (lane >> 4) * 8 + i;
    int n = nt * 16 + (lane & 15);
    float v = (k < 48) ? w1[n * 48 + k] : 0.f;
    _Float16 h = (_Float16)v;
    w1fh[t] = h;
    w1fl[t] = (_Float16)(v - (float)h);
  } else {
    int u = t - 8192;                        // 2048 threads
    int lane = (u >> 3) & 63, i = u & 7;
    int kt = u >> 9;
    int g = (lane >> 4) & 3;
    int o = lane & 15;
    int kk = (i < 4) ? (4 * g + i) : (16 + 4 * g + (i - 4));
    float v = w2[o * HIDN + kt * 32 + kk];
    _Float16 h = (_Float16)v;
    w2fh[u] = h;
    w2fl[u] = (_Float16)(v - (float)h);
  }
}

// MFMA step kernel — r6 math, XCD-residency block mapping (byte-identical
// to round 11). Blocks [0,1024): step work, b = blk&7, y = blk>>3.
// Blocks [1024,1024+256) (when s<7): generate NEXT step's mask words.
__global__ __launch_bounds__(256, 3) void step_mfma(
    const float* __restrict__ s,
    const f16x8* __restrict__ w1fh, const f16x8* __restrict__ w1fl,
    const f16x8* __restrict__ w2fh, const f16x8* __restrict__ w2fl,
    const float* __restrict__ bias1, const float* __restrict__ bias2,
    const unsigned* __restrict__ mask,   // this step's words (read)
    unsigned* __restrict__ maskN,        // next step's words (tail writes)
    const unsigned kn0, const unsigned kn1,  // next step's threefry key
    float* __restrict__ mid,
    const float* __restrict__ mid3cR,   // prev step's ch3 snapshot
    float* __restrict__ mid3cW,         // this step's ch3 snapshot
    const unsigned char* __restrict__ preR,  // prev step's pre bits
    unsigned char* __restrict__ preW,        // this step's pre bits
    const int hasKill) {
  if (blockIdx.x >= STEP_BLOCKS) {     // mask-gen tail block
    const unsigned wid = (blockIdx.x - STEP_BLOCKS) * 256u + threadIdx.x;
    maskN[wid] = mask_word(kn0, kn1, wid);
    return;
  }

  __shared__ __align__(16) char smem[4 * WREG];
  const int tid = threadIdx.x;
  const int wv = tid >> 6;
  const int l  = tid & 63;
  const int p  = l & 15;        // MFMA row/col lane index
  const int g  = l >> 4;        // lane group (k-group for frags)
  char* wb = smem + wv * WREG;
  _Float16* Phi = (_Float16*)wb;
  _Float16* Plo = (_Float16*)(wb + PLO_OFF);
  float*    kcm = (float*)(wb + KCM_OFF);   // [3][36] col-max of 3 rows
  float*    kfl = (float*)(wb + KF_OFF);    // [3][36] kill factors

  // XCD-residency mapping: image b lives on XCD (blockIdx%8) every step.
  const int b  = (int)(blockIdx.x & 7);
  const int y  = (int)(blockIdx.x >> 3);
  const int x0 = wv * 32;
  const int pid0 = ((b << 7) + y) * 128 + x0;   // wave's first pixel
  const bool yu = (y > 0), yd = (y < HT - 1);

  // ---- kill table via colmax: kcm[kr][kc] = max over 3 rows of col ----
  if (hasKill) {
    const float* m3 = mid3cR + b * PLANE;
    #pragma unroll
    for (int rr = 0; rr < 2; ++rr) {
      const int e = l + rr * 64;
      if (e < 108) {
        const int kr = e / 36;            // output row y-1+kr
        const int kc = e - kr * 36;       // col x0-2+kc
        const int xx = x0 - 2 + kc;
        float cm = -1e30f;
        if ((unsigned)xx < WD) {
          #pragma unroll
          for (int dr = -1; dr <= 1; ++dr) {
            const int ry = y - 1 + kr + dr;
            if ((unsigned)ry < HT) cm = fmaxf(cm, m3[ry * WD + xx]);
          }
        }
        kcm[kr * 36 + kc] = cm;
      }
    }
    MEM_FENCE();  // kcm writes before kcm reads
    const unsigned char* prb = preR + b * PLANE;
    #pragma unroll
    for (int rr = 0; rr < 2; ++rr) {
      const int e = l + rr * 64;
      if (e < 102) {
        const int kr = e / 34;
        const int kc = e - kr * 34;
        const int yy = y - 1 + kr;
        const int xx = x0 - 1 + kc;
        float kf = 0.f;
        if ((unsigned)yy < HT && (unsigned)xx < WD) {
          const float* c0 = kcm + kr * 36 + kc;
          float mx = fmaxf(fmaxf(c0[0], c0[1]), c0[2]);
          kf = ((mx > 0.1f) && prb[yy * WD + xx]) ? 1.f : 0.f;
        }
        kfl[kr * 36 + kc] = kf;
      }
    }
  } else {
    #pragma unroll
    for (int rr = 0; rr < 2; ++rr) {
      const int e = l + rr * 64;
      if (e < 108) kfl[e] = 1.f;          // [3][36] all-alive
    }
  }

  // Early independent loads (overlap with perceive).
  const float4 b2q = *(const float4*)(bias2 + g * 4);
  unsigned mw[4];
  #pragma unroll
  for (int cc = 0; cc < 4; ++cc)
    mw[cc] = mask[((b * CH + g * 4 + cc) * HT + y) * (WD / 32) + (x0 >> 5)];

  // Zero-pad P feats 48..63 (16 rows x {hi,lo}): one 16B chunk per lane.
  {
    uint4 z; z.x = 0u; z.y = 0u; z.z = 0u; z.w = 0u;
    _Float16* zb = (l & 32) ? Plo : Phi;
    *(uint4*)(zb + (l & 15) * PSTR + 48 + ((l >> 4) & 1) * 8) = z;
  }

  MEM_FENCE();  // kill-table/pad writes before reads

  // ---- perceive both tiles, tile-sequenced through the SAME P region ----
  const float* sb = s + b * IMG;
  float sctr[2][4];
  float premax[2] = {-1e30f, -1e30f};
  f16x8 pbh[2][2], pbl[2][2];   // P B-fragments (hi/lo, kt=0/1) per tile
  #pragma unroll
  for (int t = 0; t < 2; ++t) {
    const int xt = x0 + 16 * t + p;
    const int ctr = y * WD + xt;
    const bool xl = (xt > 0), xr = (xt < WD - 1);
    float kf9[9];
    {
      const int kc = 16 * t + p;
      #pragma unroll
      for (int dy2 = 0; dy2 < 3; ++dy2)
        #pragma unroll
        for (int dx2 = 0; dx2 < 3; ++dx2)
          kf9[dy2 * 3 + dx2] = kfl[dy2 * 36 + kc + dx2];
    }
    f16x4 vh0, vh1, vh2, vl0, vl1, vl2;
    #pragma unroll
    for (int cc = 0; cc < 4; ++cc) {
      const int c = g * 4 + cc;
      const float* sc = sb + c * PLANE + ctr;
      float a11 = sc[0] * kf9[4];
      float a00 = ((yu && xl) ? sc[-WD - 1] : 0.f) * kf9[0];
      float a01 = (yu         ? sc[-WD]     : 0.f) * kf9[1];
      float a02 = ((yu && xr) ? sc[-WD + 1] : 0.f) * kf9[2];
      float a10 = (xl         ? sc[-1]      : 0.f) * kf9[3];
      float a12 = (xr         ? sc[1]       : 0.f) * kf9[5];
      float a20 = ((yd && xl) ? sc[WD - 1]  : 0.f) * kf9[6];
      float a21 = (yd         ? sc[WD]      : 0.f) * kf9[7];
      float a22 = ((yd && xr) ? sc[WD + 1]  : 0.f) * kf9[8];
      float sx = (a02 - a00) + 2.f * (a12 - a10) + (a22 - a20);
      float sy = (a20 - a00) + 2.f * (a21 - a01) + (a22 - a02);
      sctr[t][cc] = a11;
      _Float16 h0 = (_Float16)a11;
      _Float16 h1 = (_Float16)sx;
      _Float16 h2 = (_Float16)sy;
      vh0[cc] = h0; vl0[cc] = (_Float16)(a11 - (float)h0);
      vh1[cc] = h1; vl1[cc] = (_Float16)(sx - (float)h1);
      vh2[cc] = h2; vl2[cc] = (_Float16)(sy - (float)h2);
      if (g == 0 && cc == 3) {   // alive channel: pre-update maxpool (killed)
        float m0 = fmaxf(fmaxf(a00, a01), fmaxf(a02, a10));
        float m1 = fmaxf(fmaxf(a11, a12), fmaxf(a20, a21));
        premax[t] = fmaxf(fmaxf(m0, m1), a22);
      }
    }
    *(f16x4*)(Phi + p * PSTR + 4 * g)      = vh0;
    *(f16x4*)(Phi + p * PSTR + 16 + 4 * g) = vh1;
    *(f16x4*)(Phi + p * PSTR + 32 + 4 * g) = vh2;
    *(f16x4*)(Plo + p * PSTR + 4 * g)      = vl0;
    *(f16x4*)(Plo + p * PSTR + 16 + 4 * g) = vl1;
    *(f16x4*)(Plo + p * PSTR + 32 + 4 * g) = vl2;
    MEM_FENCE();  // P writes before B-frag reads
    const _Float16* prow = Phi + p * PSTR;
    const _Float16* lrow = Plo + p * PSTR;
    pbh[t][0] = *(const f16x8*)(prow + g * 8);
    pbh[t][1] = *(const f16x8*)(prow + 32 + g * 8);
    pbl[t][0] = *(const f16x8*)(lrow + g * 8);
    pbl[t][1] = *(const f16x8*)(lrow + 32 + g * 8);
    MEM_FENCE();  // B-frag reads before tile1 P writes
  }

  // ---- GEMM1 (swapped): acc[t][nt] = bias1 + W1 x P, split-f16.
  // D1[row=hidden nt*16+g*4+q][col=pixel p]: lane holds ITS pixel's hiddens.
  f32x4 acc[2][8];
  #pragma unroll
  for (int nt = 0; nt < 8; ++nt) {
    const float4 bq = *(const float4*)(bias1 + nt * 16 + 4 * g);
    f32x4 v = {bq.x, bq.y, bq.z, bq.w};
    acc[0][nt] = v;
    acc[1][nt] = v;
  }
  #pragma unroll
  for (int nt = 0; nt < 8; ++nt) {
    f16x8 w1h0 = w1fh[nt * 64 + l];
    f16x8 w1h1 = w1fh[512 + nt * 64 + l];
    f16x8 w1l0 = w1fl[nt * 64 + l];
    f16x8 w1l1 = w1fl[512 + nt * 64 + l];
    #pragma unroll
    for (int t = 0; t < 2; ++t) {
      acc[t][nt] = __builtin_amdgcn_mfma_f32_16x16x32_f16(w1h0, pbh[t][0], acc[t][nt], 0, 0, 0);
      acc[t][nt] = __builtin_amdgcn_mfma_f32_16x16x32_f16(w1h1, pbh[t][1], acc[t][nt], 0, 0, 0);
      acc[t][nt] = __builtin_amdgcn_mfma_f32_16x16x32_f16(w1l0, pbh[t][0], acc[t][nt], 0, 0, 0);
      acc[t][nt] = __builtin_amdgcn_mfma_f32_16x16x32_f16(w1l1, pbh[t][1], acc[t][nt], 0, 0, 0);
      acc[t][nt] = __builtin_amdgcn_mfma_f32_16x16x32_f16(w1h0, pbl[t][0], acc[t][nt], 0, 0, 0);
      acc[t][nt] = __builtin_amdgcn_mfma_f32_16x16x32_f16(w1h1, pbl[t][1], acc[t][nt], 0, 0, 0);
    }
  }

  // GEMM2 W2 A-fragments (sigma-packed; shared by both tiles).
  f16x8 w2h[4], w2l[4];
  #pragma unroll
  for (int kt = 0; kt < 4; ++kt) {
    w2h[kt] = w2fh[kt * 64 + l];
    w2l[kt] = w2fl[kt * 64 + l];
  }

  // ---- H in registers + GEMM2 per tile ----
  // B-frag slot i of kt holds hidden kt*32 + sigma(g,i):
  //   i<4 -> acc[2kt][i]; i>=4 -> acc[2kt+1][i-4].
  f32x4 dxr[2];
  #pragma unroll
  for (int t = 0; t < 2; ++t) {
    f16x8 hB[4], lB[4];
    #pragma unroll
    for (int kt = 0; kt < 4; ++kt) {
      #pragma unroll
      for (int i2 = 0; i2 < 4; ++i2) {
        float h0 = fmaxf(acc[t][2 * kt][i2], 0.f);
        _Float16 hh0 = (_Float16)h0;
        hB[kt][i2] = hh0;
        lB[kt][i2] = (_Float16)(h0 - (float)hh0);
        float h1 = fmaxf(acc[t][2 * kt + 1][i2], 0.f);
        _Float16 hh1 = (_Float16)h1;
        hB[kt][4 + i2] = hh1;
        lB[kt][4 + i2] = (_Float16)(h1 - (float)hh1);
      }
    }
    f32x4 accP = {b2q.x, b2q.y, b2q.z, b2q.w};
    f32x4 accQ = {0.f, 0.f, 0.f, 0.f};
    f32x4 accR = {0.f, 0.f, 0.f, 0.f};
    #pragma unroll
    for (int kt = 0; kt < 4; ++kt) {
      accP = __builtin_amdgcn_mfma_f32_16x16x32_f16(w2h[kt], hB[kt], accP, 0, 0, 0);
      accQ = __builtin_amdgcn_mfma_f32_16x16x32_f16(w2l[kt], hB[kt], accQ, 0, 0, 0);
      accR = __builtin_amdgcn_mfma_f32_16x16x32_f16(w2h[kt], lB[kt], accR, 0, 0, 0);
    }
    dxr[t] = (accP + accQ) + accR;
  }

  if (g == 0) {
    preW[pid0 + p]      = (premax[0] > 0.1f) ? 1 : 0;
    preW[pid0 + 16 + p] = (premax[1] > 0.1f) ? 1 : 0;
  }

  // ---- epilogue: lane -> (pixel 16t+p, channels 4g..4g+3). mid stays
  // UNMASKED (next step / step_b applies the kill). Coalesced stores.
  #pragma unroll
  for (int t = 0; t < 2; ++t) {
    const int xt = x0 + 16 * t + p;
    const int rt = y * WD + xt;
    #pragma unroll
    for (int cc = 0; cc < 4; ++cc) {
      const int c = g * 4 + cc;
      float d = dxr[t][cc];
      d = fminf(fmaxf(d, -5.f), 5.f);
      float v = sctr[t][cc] + (((mw[cc] >> (16 * t + p)) & 1u) ? d : 0.f);
      mid[b * IMG + c * PLANE + rt] = v;
      if (g == 0 && cc == 3) mid3cW[pid0 + 16 * t + p] = v;  // ch3 snapshot
    }
  }
}

// Final post-alive maxpool + apply pre&post (reads RAW mid). Block index
// permuted so batch b's blocks land on XCD b (hardware blockIdx%8).
__global__ __launch_bounds__(256) void step_b(
    const float* __restrict__ mid,
    const unsigned char* __restrict__ pre,
    float* __restrict__ out) {
  const unsigned h = blockIdx.x;            // 512 blocks
  const unsigned j = h >> 3;
  const unsigned kl = ((j >> 4) << 7) | ((h & 7) << 4) | (j & 15);
  int t = (int)kl * 256 + threadIdx.x;      // same (cq,b,r) coverage
  int cq = t >> 15;
  int qid = t & 32767;
  int b = qid >> 12;
  int r = qid & 4095;
  int y = r >> 5;
  int x0 = (r & 31) * 4;
  const float* m3 = mid + b * IMG + 3 * PLANE;

  float col[6];
  #pragma unroll
  for (int j2 = 0; j2 < 6; ++j2) {
    int xx = x0 - 1 + j2;
    float m = -1e30f;
    if ((unsigned)xx < WD) {
      #pragma unroll
      for (int dy = -1; dy <= 1; ++dy) {
        int yy = y + dy;
        if ((unsigned)yy < HT) m = fmaxf(m, m3[yy * WD + xx]);
      }
    }
    col[j2] = m;
  }

  const unsigned char* pr = pre + b * PLANE + y * WD + x0;
  float f[4];
  #pragma unroll
  for (int i = 0; i < 4; ++i) {
    float mx = fmaxf(fmaxf(col[i], col[i + 1]), col[i + 2]);
    f[i] = ((mx > 0.1f) && pr[i]) ? 1.f : 0.f;
  }

  #pragma unroll
  for (int cc = 0; cc < 4; ++cc) {
    int c = cq * 4 + cc;
    const float4 v = *(const float4*)&mid[b * IMG + c * PLANE + y * WD + x0];
    float4 w;
    w.x = v.x * f[0]; w.y = v.y * f[1]; w.z = v.z * f[2]; w.w = v.w * f[3];
    *(float4*)&out[b * IMG + c * PLANE + y * WD + x0] = w;
  }
}

extern "C" void kernel_launch(void* const* d_in, const int* in_sizes, int n_in,
                              void* d_out, int out_size, void* d_ws, size_t ws_size,
                              hipStream_t stream) {
  const float* x  = (const float*)d_in[0];
  const float* w1 = (const float*)d_in[1];
  const float* b1 = (const float*)d_in[2];
  const float* w2 = (const float*)d_in[3];
  const float* b2 = (const float*)d_in[4];
  float* out = (float*)d_out;

  char* ws = (char*)d_ws;
  float* midbuf[2];
  midbuf[0] = (float*)ws;
  midbuf[1] = (float*)(ws + (size_t)NELEM * 4);
  float* m3b[2];
  m3b[0] = (float*)(ws + 2 * (size_t)NELEM * 4);
  m3b[1] = m3b[0] + NPIX;
  unsigned char* preb[2];
  preb[0] = (unsigned char*)(ws + 2 * (size_t)NELEM * 4 + 2 * (size_t)NPIX * 4);
  preb[1] = preb[0] + NPIX;
  unsigned* mask = (unsigned*)(ws + 2 * (size_t)NELEM * 4
                                  + 2 * (size_t)NPIX * 4 + 2 * (size_t)NPIX);
  _Float16* w1fh = (_Float16*)((char*)mask
                               + (size_t)NSTEPS * WORDS_PER_STEP * 4);
  _Float16* w1fl = w1fh + 8192;
  _Float16* w2fh = w1fl + 8192;
  _Float16* w2fl = w2fh + 2048;

  // keys = jax.random.split(key(42), 8): keys[j] = threefry2x32((0,42),(0,j))
  Keys keys;
  for (int j = 0; j < NSTEPS; ++j) {
    unsigned a, b;
    tf2x32(0u, 42u, 0u, (unsigned)j, a, b);
    keys.k[2 * j] = a; keys.k[2 * j + 1] = b;
  }

  // wpack + step-0 mask + x-prefetch in one launch.
  wpack_kernel<<<40 + MASK_BLOCKS + PREF_BLOCKS, 256, 0, stream>>>(
      x, w1, w2, w1fh, w1fl, w2fh, w2fl, mask, keys.k[0], keys.k[1]);

  for (int s = 0; s < NSTEPS; ++s) {
    const float* src = (s == 0) ? x : midbuf[(s - 1) & 1];
    const int cur = s & 1, prv = cur ^ 1;
    const bool genNext = (s + 1 < NSTEPS);
    step_mfma<<<STEP_BLOCKS + (genNext ? MASK_BLOCKS : 0), 256, 0, stream>>>(
        src,
        (const f16x8*)w1fh, (const f16x8*)w1fl,
        (const f16x8*)w2fh, (const f16x8*)w2fl,
        b1, b2,
        mask + s * WORDS_PER_STEP,
        mask + (genNext ? (s + 1) : s) * WORDS_PER_STEP,  // tail writes (unused when s=7)
        keys.k[2 * (genNext ? (s + 1) : s)],
        keys.k[2 * (genNext ? (s + 1) : s) + 1],
        midbuf[cur],
        m3b[prv], m3b[cur],     // read prev snapshot, write own
        preb[prv], preb[cur],   // read prev pre bits, write own
        (s > 0) ? 1 : 0);
  }
  step_b<<<NPIX / 256, 256, 0, stream>>>(
      midbuf[(NSTEPS - 1) & 1], preb[(NSTEPS - 1) & 1], out);
}